// Round 3
// baseline (327.993 us; speedup 1.0000x reference)
//
#include <hip/hip_runtime.h>
#include <hip/hip_bf16.h>
#include <math.h>

#define L 2048
#define D 256
#define NEG_FLT_MAX (-3.402823466e38f)

typedef __attribute__((ext_vector_type(8))) short bf16x8;
typedef __attribute__((ext_vector_type(4))) float f32x4;
typedef __attribute__((ext_vector_type(4))) int i32x4;

__device__ __forceinline__ unsigned short f2bf(float f) {
    union { float f; unsigned int u; } v; v.f = f;
    unsigned int r = v.u + 0x7FFFu + ((v.u >> 16) & 1u);   // RNE
    return (unsigned short)(r >> 16);
}

// --- transpose Wv, Wo (f32 k-major) -> bf16 n-major ---------------------
__global__ __launch_bounds__(256) void wtrans_kernel(
    const float* __restrict__ Wv, const float* __restrict__ Wo,
    unsigned short* __restrict__ Wvt, unsigned short* __restrict__ Wot) {
    int idx = blockIdx.x * 256 + threadIdx.x;       // 0..131071
    int which = idx >> 16;
    int e = idx & 65535;
    int k = e >> 8, n = e & 255;
    const float* W = which ? Wo : Wv;
    unsigned short* Wt = which ? Wot : Wvt;
    Wt[n * 256 + k] = f2bf(W[k * 256 + n]);
}

// --- v-projection GEMM: Vt[b][n][j] = bf16( value @ Wv + bv ) -----------
// 32x64 tile, grid (256,4) = 1024 blocks -> 4 blocks/CU = 16 waves/CU
__global__ __launch_bounds__(256) void gemm_v_kernel(
    const float* __restrict__ A,
    const unsigned short* __restrict__ Wt,   // [256][256] bf16 n-major
    const float* __restrict__ bias,
    unsigned short* __restrict__ Vt) {
    const int wave = threadIdx.x >> 6;
    const int lane = threadIdx.x & 63;
    const int lm = lane & 15, q = lane >> 4;
    const int rh = wave >> 1;          // row half (16 rows each)
    const int nh = wave & 1;           // n half (32 cols each)
    const int m0 = blockIdx.x * 32;
    const int n0 = blockIdx.y * 64;
    const int arow = m0 + rh * 16 + lm;

    int ncol[2];
#pragma unroll
    for (int nf = 0; nf < 2; nf++) ncol[nf] = n0 + nh * 32 + nf * 16 + lm;

    f32x4 acc[2];
    acc[0] = (f32x4)(0.f); acc[1] = (f32x4)(0.f);

    const float* ap = A + (size_t)arow * 256;
    f32x4 pa0 = *reinterpret_cast<const f32x4*>(ap + q * 8);
    f32x4 pa1 = *reinterpret_cast<const f32x4*>(ap + q * 8 + 4);
    bf16x8 pb0 = *reinterpret_cast<const bf16x8*>(Wt + (size_t)ncol[0] * 256 + q * 8);
    bf16x8 pb1 = *reinterpret_cast<const bf16x8*>(Wt + (size_t)ncol[1] * 256 + q * 8);

    for (int k0 = 0; k0 < 256; k0 += 32) {
        f32x4 a0 = pa0, a1 = pa1;
        bf16x8 b0 = pb0, b1 = pb1;
        if (k0 < 224) {
            int kq = k0 + 32 + q * 8;
            pa0 = *reinterpret_cast<const f32x4*>(ap + kq);
            pa1 = *reinterpret_cast<const f32x4*>(ap + kq + 4);
            pb0 = *reinterpret_cast<const bf16x8*>(Wt + (size_t)ncol[0] * 256 + kq);
            pb1 = *reinterpret_cast<const bf16x8*>(Wt + (size_t)ncol[1] * 256 + kq);
        }
        bf16x8 afr;
#pragma unroll
        for (int e = 0; e < 4; e++) afr[e] = (short)f2bf(a0[e]);
#pragma unroll
        for (int e = 0; e < 4; e++) afr[4 + e] = (short)f2bf(a1[e]);
        acc[0] = __builtin_amdgcn_mfma_f32_16x16x32_bf16(afr, b0, acc[0], 0, 0, 0);
        acc[1] = __builtin_amdgcn_mfma_f32_16x16x32_bf16(afr, b1, acc[1], 0, 0, 0);
    }

    int mrow = m0 + rh * 16 + q * 4;      // rows mrow..mrow+3
    int b = mrow >> 11;
    int j = mrow & 2047;
#pragma unroll
    for (int nf = 0; nf < 2; nf++) {
        int n = ncol[nf];
        float bias_n = bias[n];
        unsigned short* dst = Vt + (size_t)b * (D * L) + (size_t)n * L + j;
        ushort4 pk;
        pk.x = f2bf(acc[nf][0] + bias_n);
        pk.y = f2bf(acc[nf][1] + bias_n);
        pk.z = f2bf(acc[nf][2] + bias_n);
        pk.w = f2bf(acc[nf][3] + bias_n);
        *reinterpret_cast<ushort4*>(dst) = pk;
    }
}

// --- fused mask + no-max softmax + P@V + /l + @Wo, BARRIER-FREE loop ----
// One block = 16 output rows, all 2048 j. 512 thr = 8 waves:
//   kg = wave>>2 : j-half of each 128-j tile (additive accumulators)
//   ng = wave&3  : 64-col n range
// Each wave computes its OWN P A-fragment from global (lane lm = row,
// q*8 = j-slice): 4x redundant exp across ng-waves (~2.5us total) buys
// ZERO main-loop barriers and no Plds round-trip. a/mask/pad re-reads
// across ng hit L1/L2 (same CU), so HBM bytes stay at the mandatory ~190MB.
__global__ __launch_bounds__(512, 4) void attn_kernel(
    const float* __restrict__ atten, const float* __restrict__ mask,
    const int* __restrict__ pad, const unsigned short* __restrict__ Vt,
    const unsigned short* __restrict__ Wot, const float* __restrict__ bo,
    float* __restrict__ out) {
    const int g = blockIdx.x;          // 0..511
    const int b = g >> 7;
    const int i0 = (g & 127) * 16;
    const int tid = threadIdx.x;
    const int wave = tid >> 6, lane = tid & 63;
    const int lm = lane & 15, q = lane >> 4;
    const int kg = wave >> 2;          // j-half of tile (0/1)
    const int ng = wave & 3;           // n range (64 cols)

    __shared__ float acc_lds[16][258];
    __shared__ __align__(16) unsigned short A_lds[16][264];
    __shared__ float l_part[2][16];

    f32x4 acc[4];
#pragma unroll
    for (int nf = 0; nf < 4; nf++) acc[nf] = (f32x4)(0.f);
    float lsum = 0.f;

    // per-lane A-fragment source: row i0+lm, j base kg*64 + q*8
    const size_t rowoff = ((size_t)(b * L + i0 + lm)) * L + kg * 64 + q * 8;
    const float* at_p = atten + rowoff;
    const float* mk_p = mask + rowoff;
    const int*   pd_p = pad + rowoff;
    const unsigned short* vt_b = Vt + (size_t)b * (D * L) + kg * 64 + q * 8;

    // prefetch tile 0: 4 f32x4 per stream (kk=0 at +0,+4; kk=1 at +32,+36)
    f32x4 pa[4], pm[4];
    i32x4 pp[4];
#pragma unroll
    for (int u = 0; u < 4; u++) {
        int off = (u >> 1) * 32 + (u & 1) * 4;
        pa[u] = *reinterpret_cast<const f32x4*>(at_p + off);
        pm[u] = *reinterpret_cast<const f32x4*>(mk_p + off);
        pp[u] = *reinterpret_cast<const i32x4*>(pd_p + off);
    }

    for (int jt = 0; jt < 16; jt++) {
        const int j0 = jt * 128;
        // B fragments from Vt (L2-resident) -- issue first, consumed last
        bf16x8 bfr[2][4];
#pragma unroll
        for (int kk = 0; kk < 2; kk++)
#pragma unroll
            for (int nf = 0; nf < 4; nf++) {
                int n = ng * 64 + nf * 16 + lm;
                bfr[kk][nf] = *reinterpret_cast<const bf16x8*>(
                    vt_b + (size_t)n * L + j0 + kk * 32);
            }
        // consume prefetched logits/masks
        f32x4 ca[4], cm[4];
        i32x4 cp[4];
#pragma unroll
        for (int u = 0; u < 4; u++) { ca[u] = pa[u]; cm[u] = pm[u]; cp[u] = pp[u]; }
        if (jt < 15) {
#pragma unroll
            for (int u = 0; u < 4; u++) {
                int off = j0 + 128 + (u >> 1) * 32 + (u & 1) * 4;
                pa[u] = *reinterpret_cast<const f32x4*>(at_p + off);
                pm[u] = *reinterpret_cast<const f32x4*>(mk_p + off);
                pp[u] = *reinterpret_cast<const i32x4*>(pd_p + off);
            }
        }
        // masked exp (no max subtraction: masked -> exp underflows to 0)
        bf16x8 afr[2];
#pragma unroll
        for (int u = 0; u < 4; u++) {
            int kk = u >> 1, h = u & 1;
#pragma unroll
            for (int e = 0; e < 4; e++) {
                float sv = (cm[u][e] < 0.5f) ? NEG_FLT_MAX : ca[u][e];
                sv = (cp[u][e] == 0) ? -INFINITY : sv;
                float pv = __expf(sv);
                lsum += pv;
                afr[kk][h * 4 + e] = (short)f2bf(pv);
            }
        }
        // P @ V for this wave's (kg, ng) quarter
#pragma unroll
        for (int kk = 0; kk < 2; kk++)
#pragma unroll
            for (int nf = 0; nf < 4; nf++)
                acc[nf] = __builtin_amdgcn_mfma_f32_16x16x32_bf16(
                    afr[kk], bfr[kk][nf], acc[nf], 0, 0, 0);
    }

    // l: sum over q-group (lanes lm, lm+16, lm+32, lm+48 share row lm)
    lsum += __shfl_xor(lsum, 16);
    lsum += __shfl_xor(lsum, 32);
    if (ng == 0 && q == 0) l_part[kg][lm] = lsum;

    // kg=1 deposits accumulators
    if (kg == 1) {
#pragma unroll
        for (int nf = 0; nf < 4; nf++) {
            int n = ng * 64 + nf * 16 + lm;
#pragma unroll
            for (int rg = 0; rg < 4; rg++)
                acc_lds[q * 4 + rg][n] = acc[nf][rg];
        }
    }
    __syncthreads();

    // kg=0 combines halves, divides by l, packs bf16 A for out-projection
    if (kg == 0) {
#pragma unroll
        for (int nf = 0; nf < 4; nf++) {
            int n = ng * 64 + nf * 16 + lm;
#pragma unroll
            for (int rg = 0; rg < 4; rg++) {
                int rr = q * 4 + rg;
                float tot = acc[nf][rg] + acc_lds[rr][n];
                float lv = l_part[0][rr] + l_part[1][rr];
                A_lds[rr][n] = f2bf(tot / lv);
            }
        }
    }
    __syncthreads();

    // out-projection: [16][256] @ Wo + bo, all 8 waves (32 n each)
    f32x4 oacc[2];
    oacc[0] = (f32x4)(0.f); oacc[1] = (f32x4)(0.f);
    for (int k0 = 0; k0 < 256; k0 += 32) {
        bf16x8 afr = *reinterpret_cast<const bf16x8*>(&A_lds[lm][k0 + q * 8]);
#pragma unroll
        for (int nf = 0; nf < 2; nf++) {
            int n = wave * 32 + nf * 16 + lm;
            bf16x8 bfr = *reinterpret_cast<const bf16x8*>(
                Wot + (size_t)n * 256 + k0 + q * 8);
            oacc[nf] = __builtin_amdgcn_mfma_f32_16x16x32_bf16(
                afr, bfr, oacc[nf], 0, 0, 0);
        }
    }
#pragma unroll
    for (int nf = 0; nf < 2; nf++) {
        int n = wave * 32 + nf * 16 + lm;
        float bias_n = bo[n];
#pragma unroll
        for (int rg = 0; rg < 4; rg++)
            out[((size_t)(b * L + i0 + q * 4 + rg)) * 256 + n] = oacc[nf][rg] + bias_n;
    }
}

extern "C" void kernel_launch(void* const* d_in, const int* in_sizes, int n_in,
                              void* d_out, int out_size, void* d_ws, size_t ws_size,
                              hipStream_t stream) {
    (void)in_sizes; (void)n_in; (void)out_size; (void)ws_size;
    const float* atten = (const float*)d_in[0];
    const float* value = (const float*)d_in[1];
    const float* mask  = (const float*)d_in[2];
    const int*   pad   = (const int*)d_in[3];
    const float* Wv    = (const float*)d_in[4];
    const float* bv    = (const float*)d_in[5];
    const float* Wo    = (const float*)d_in[6];
    const float* bo    = (const float*)d_in[7];
    float* out = (float*)d_out;

    char* ws = (char*)d_ws;
    unsigned short* Vt  = (unsigned short*)(ws);              // 4 MB  bf16 [B][D][L]
    unsigned short* Wvt = (unsigned short*)(ws + 4194304);    // 128 KB
    unsigned short* Wot = (unsigned short*)(ws + 4325376);    // 128 KB

    wtrans_kernel<<<512, 256, 0, stream>>>(Wv, Wo, Wvt, Wot);
    gemm_v_kernel<<<dim3(256, 4), 256, 0, stream>>>(value, Wvt, bv, Vt);
    attn_kernel<<<512, 512, 0, stream>>>(atten, mask, pad, Vt, Wot, bo, out);
}

// Round 4
// 254.122 us; speedup vs baseline: 1.2907x; 1.2907x over previous
//
#include <hip/hip_runtime.h>
#include <hip/hip_bf16.h>
#include <math.h>

#define L 2048
#define D 256
#define NEG_FLT_MAX (-3.402823466e38f)

typedef __attribute__((ext_vector_type(8))) short bf16x8;
typedef __attribute__((ext_vector_type(4))) float f32x4;
typedef __attribute__((ext_vector_type(4))) int i32x4;

__device__ __forceinline__ unsigned short f2bf(float f) {
    union { float f; unsigned int u; } v; v.f = f;
    unsigned int r = v.u + 0x7FFFu + ((v.u >> 16) & 1u);   // RNE
    return (unsigned short)(r >> 16);
}

// --- prep: fused {Wv transpose -> LDS} + {value @ Wv + bv -> Vt bf16}
//     + side-job {Wo transpose -> Wot global}
// 32x64 tile, grid (256,4) = 1024 blocks -> 4 blocks/CU
__global__ __launch_bounds__(256, 4) void prep_kernel(
    const float* __restrict__ value, const float* __restrict__ Wv,
    const float* __restrict__ bv, const float* __restrict__ Wo,
    unsigned short* __restrict__ Vt, unsigned short* __restrict__ Wot) {
    const int tid = threadIdx.x;
    const int wave = tid >> 6, lane = tid & 63;
    const int lm = lane & 15, q = lane >> 4;
    const int rh = wave >> 1;          // row half (16 rows each)
    const int nh = wave & 1;           // n half (32 cols each)
    const int m0 = blockIdx.x * 32;
    const int n0 = blockIdx.y * 64;

    __shared__ __align__(16) unsigned short Wlds[64][264];   // [n-local][k] bf16

    // side job: Wo transpose (64 elements per block, 1024 blocks cover 64K)
    {
        int bid = blockIdx.y * 256 + blockIdx.x;
        if (tid < 64) {
            int e = bid * 64 + tid;
            int k = e >> 8, n = e & 255;
            Wot[n * 256 + k] = f2bf(Wo[k * 256 + n]);
        }
    }

    // stage Wv[0:256][n0:n0+64] -> Wlds[n][k], coalesced f32 reads
    {
        int krow = tid >> 4;           // 0..15
        int nrel = (tid & 15) * 4;     // 0..60
#pragma unroll
        for (int p = 0; p < 16; p++) {
            int k = p * 16 + krow;
            f32x4 w = *reinterpret_cast<const f32x4*>(Wv + (size_t)k * 256 + n0 + nrel);
            Wlds[nrel + 0][k] = f2bf(w[0]);
            Wlds[nrel + 1][k] = f2bf(w[1]);
            Wlds[nrel + 2][k] = f2bf(w[2]);
            Wlds[nrel + 3][k] = f2bf(w[3]);
        }
    }
    __syncthreads();

    const int nl0 = nh * 32 + lm;          // local n, fragment 0
    const int nl1 = nh * 32 + 16 + lm;     // local n, fragment 1
    const int arow = m0 + rh * 16 + lm;

    f32x4 acc[2];
    acc[0] = (f32x4)(0.f); acc[1] = (f32x4)(0.f);

    const float* ap = value + (size_t)arow * 256;
    f32x4 pa0 = *reinterpret_cast<const f32x4*>(ap + q * 8);
    f32x4 pa1 = *reinterpret_cast<const f32x4*>(ap + q * 8 + 4);

    for (int k0 = 0; k0 < 256; k0 += 32) {
        f32x4 a0 = pa0, a1 = pa1;
        if (k0 < 224) {
            int kq = k0 + 32 + q * 8;
            pa0 = *reinterpret_cast<const f32x4*>(ap + kq);
            pa1 = *reinterpret_cast<const f32x4*>(ap + kq + 4);
        }
        bf16x8 b0 = *reinterpret_cast<const bf16x8*>(&Wlds[nl0][k0 + q * 8]);
        bf16x8 b1 = *reinterpret_cast<const bf16x8*>(&Wlds[nl1][k0 + q * 8]);
        bf16x8 afr;
#pragma unroll
        for (int e = 0; e < 4; e++) afr[e] = (short)f2bf(a0[e]);
#pragma unroll
        for (int e = 0; e < 4; e++) afr[4 + e] = (short)f2bf(a1[e]);
        acc[0] = __builtin_amdgcn_mfma_f32_16x16x32_bf16(afr, b0, acc[0], 0, 0, 0);
        acc[1] = __builtin_amdgcn_mfma_f32_16x16x32_bf16(afr, b1, acc[1], 0, 0, 0);
    }

    int mrow = m0 + rh * 16 + q * 4;       // rows mrow..mrow+3
    int b = mrow >> 11;
    int j = mrow & 2047;
#pragma unroll
    for (int nf = 0; nf < 2; nf++) {
        int n = n0 + nh * 32 + nf * 16 + lm;
        float bias_n = bv[n];
        const f32x4& a = acc[nf];
        unsigned short* dst = Vt + (size_t)b * (D * L) + (size_t)n * L + j;
        ushort4 pk;
        pk.x = f2bf(a[0] + bias_n);
        pk.y = f2bf(a[1] + bias_n);
        pk.z = f2bf(a[2] + bias_n);
        pk.w = f2bf(a[3] + bias_n);
        *reinterpret_cast<ushort4*>(dst) = pk;
    }
}

// --- fused mask + no-max softmax + P@V + /l + @Wo + bo -> out -----------
// Round-0-proven shape: 256 thr / 4 waves, coalesced logit loads
// (lane = consecutive j), P via LDS, 1 barrier per j-tile.
// One block = 16 rows x all 2048 j (16 tiles of 128 j). No partials.
// l-reduction deferred to after the loop (register accumulation only).
__global__ __launch_bounds__(256, 2) void attn_kernel(
    const float* __restrict__ atten, const float* __restrict__ mask,
    const int* __restrict__ pad, const unsigned short* __restrict__ Vt,
    const unsigned short* __restrict__ Wot, const float* __restrict__ bo,
    float* __restrict__ out) {
    const int g = blockIdx.x;          // 0..511
    const int b = g >> 7;
    const int i0 = (g & 127) * 16;
    const int tid = threadIdx.x;
    const int wave = tid >> 6, lane = tid & 63;
    const int lm = lane & 15, q = lane >> 4;
    const int r = tid >> 4;            // softmax row 0..15
    const int c = (tid & 15) * 8;      // j offset within 128-tile

    __shared__ __align__(16) unsigned short Plds[2][16][136];
    __shared__ __align__(16) unsigned short A_lds[16][264];
    __shared__ float l_lds[16];

    f32x4 acc[4];
#pragma unroll
    for (int nf = 0; nf < 4; nf++) acc[nf] = (f32x4)(0.f);
    float lsum = 0.f;

    const size_t rowoff = ((size_t)(b * L + i0 + r)) * L + c;
    const float* at_p = atten + rowoff;
    const float* mk_p = mask + rowoff;
    const int*   pd_p = pad + rowoff;
    const unsigned short* vt_b = Vt + (size_t)b * (D * L);

    // prefetch tile 0 logits/masks (2 x f32x4 per stream)
    f32x4 pa0 = *reinterpret_cast<const f32x4*>(at_p);
    f32x4 pa1 = *reinterpret_cast<const f32x4*>(at_p + 4);
    f32x4 pm0 = *reinterpret_cast<const f32x4*>(mk_p);
    f32x4 pm1 = *reinterpret_cast<const f32x4*>(mk_p + 4);
    i32x4 pp0 = *reinterpret_cast<const i32x4*>(pd_p);
    i32x4 pp1 = *reinterpret_cast<const i32x4*>(pd_p + 4);

    for (int jt = 0; jt < 16; jt++) {
        const int j0 = jt * 128;
        // V fragments for this wave's 64-n range (L2-resident)
        bf16x8 bfr[4][4];
#pragma unroll
        for (int kk = 0; kk < 4; kk++)
#pragma unroll
            for (int nf = 0; nf < 4; nf++) {
                int n = wave * 64 + nf * 16 + lm;
                bfr[kk][nf] = *reinterpret_cast<const bf16x8*>(
                    vt_b + (size_t)n * L + j0 + kk * 32 + q * 8);
            }
        f32x4 a0 = pa0, a1 = pa1, k0 = pm0, k1 = pm1;
        i32x4 p0 = pp0, p1 = pp1;
        if (jt < 15) {                 // depth-1 prefetch of next tile
            pa0 = *reinterpret_cast<const f32x4*>(at_p + j0 + 128);
            pa1 = *reinterpret_cast<const f32x4*>(at_p + j0 + 132);
            pm0 = *reinterpret_cast<const f32x4*>(mk_p + j0 + 128);
            pm1 = *reinterpret_cast<const f32x4*>(mk_p + j0 + 132);
            pp0 = *reinterpret_cast<const i32x4*>(pd_p + j0 + 128);
            pp1 = *reinterpret_cast<const i32x4*>(pd_p + j0 + 132);
        }
        // masked exp, no max subtraction (masked -> exp underflows to 0)
        bf16x8 pk;
#pragma unroll
        for (int e = 0; e < 4; e++) {
            float sv = (k0[e] < 0.5f) ? NEG_FLT_MAX : a0[e];
            sv = (p0[e] == 0) ? -INFINITY : sv;
            float pv = __expf(sv);
            lsum += pv;
            pk[e] = (short)f2bf(pv);
            float sw = (k1[e] < 0.5f) ? NEG_FLT_MAX : a1[e];
            sw = (p1[e] == 0) ? -INFINITY : sw;
            float pw = __expf(sw);
            lsum += pw;
            pk[4 + e] = (short)f2bf(pw);
        }
        const int par = jt & 1;
        *reinterpret_cast<bf16x8*>(&Plds[par][r][c]) = pk;
        __syncthreads();

        // P @ V for this wave's 64-n range
#pragma unroll
        for (int kk = 0; kk < 4; kk++) {
            bf16x8 afr = *reinterpret_cast<const bf16x8*>(
                &Plds[par][lm][kk * 32 + q * 8]);
#pragma unroll
            for (int nf = 0; nf < 4; nf++)
                acc[nf] = __builtin_amdgcn_mfma_f32_16x16x32_bf16(
                    afr, bfr[kk][nf], acc[nf], 0, 0, 0);
        }
    }

    // deferred l-reduction: 16 threads (consecutive tids) share row r
    lsum += __shfl_xor(lsum, 1);
    lsum += __shfl_xor(lsum, 2);
    lsum += __shfl_xor(lsum, 4);
    lsum += __shfl_xor(lsum, 8);
    if ((tid & 15) == 0) l_lds[r] = lsum;
    __syncthreads();

    // normalize, pack bf16 A for the out-projection
    float linv[4];
#pragma unroll
    for (int rg = 0; rg < 4; rg++) linv[rg] = 1.f / l_lds[q * 4 + rg];
#pragma unroll
    for (int nf = 0; nf < 4; nf++) {
        int n = wave * 64 + nf * 16 + lm;
#pragma unroll
        for (int rg = 0; rg < 4; rg++)
            A_lds[q * 4 + rg][n] = f2bf(acc[nf][rg] * linv[rg]);
    }
    __syncthreads();

    // out-projection: [16][256] @ Wo + bo, each wave 64 n
    f32x4 oacc[4];
#pragma unroll
    for (int nf = 0; nf < 4; nf++) oacc[nf] = (f32x4)(0.f);
    for (int k0 = 0; k0 < 256; k0 += 32) {
        bf16x8 afr = *reinterpret_cast<const bf16x8*>(&A_lds[lm][k0 + q * 8]);
#pragma unroll
        for (int nf = 0; nf < 4; nf++) {
            int n = wave * 64 + nf * 16 + lm;
            bf16x8 bfrW = *reinterpret_cast<const bf16x8*>(
                Wot + (size_t)n * 256 + k0 + q * 8);
            oacc[nf] = __builtin_amdgcn_mfma_f32_16x16x32_bf16(
                afr, bfrW, oacc[nf], 0, 0, 0);
        }
    }
#pragma unroll
    for (int nf = 0; nf < 4; nf++) {
        int n = wave * 64 + nf * 16 + lm;
        float bias_n = bo[n];
#pragma unroll
        for (int rg = 0; rg < 4; rg++)
            out[((size_t)(b * L + i0 + q * 4 + rg)) * 256 + n] = oacc[nf][rg] + bias_n;
    }
}

extern "C" void kernel_launch(void* const* d_in, const int* in_sizes, int n_in,
                              void* d_out, int out_size, void* d_ws, size_t ws_size,
                              hipStream_t stream) {
    (void)in_sizes; (void)n_in; (void)out_size; (void)ws_size;
    const float* atten = (const float*)d_in[0];
    const float* value = (const float*)d_in[1];
    const float* mask  = (const float*)d_in[2];
    const int*   pad   = (const int*)d_in[3];
    const float* Wv    = (const float*)d_in[4];
    const float* bv    = (const float*)d_in[5];
    const float* Wo    = (const float*)d_in[6];
    const float* bo    = (const float*)d_in[7];
    float* out = (float*)d_out;

    char* ws = (char*)d_ws;
    unsigned short* Vt  = (unsigned short*)(ws);              // 4 MB  bf16 [B][D][L]
    unsigned short* Wot = (unsigned short*)(ws + 4194304);    // 128 KB

    prep_kernel<<<dim3(256, 4), 256, 0, stream>>>(value, Wv, bv, Wo, Vt, Wot);
    attn_kernel<<<512, 256, 0, stream>>>(atten, mask, pad, Vt, Wot, bo, out);
}

// Round 5
// 248.255 us; speedup vs baseline: 1.3212x; 1.0236x over previous
//
#include <hip/hip_runtime.h>
#include <hip/hip_bf16.h>
#include <math.h>

#define L 2048
#define D 256
#define NEG_FLT_MAX (-3.402823466e38f)

typedef __attribute__((ext_vector_type(8))) short bf16x8;
typedef __attribute__((ext_vector_type(4))) float f32x4;
typedef __attribute__((ext_vector_type(4))) int i32x4;

__device__ __forceinline__ unsigned short f2bf(float f) {
    union { float f; unsigned int u; } v; v.f = f;
    unsigned int r = v.u + 0x7FFFu + ((v.u >> 16) & 1u);   // RNE
    return (unsigned short)(r >> 16);
}

// --- prep: fused {Wv transpose -> LDS} + {value @ Wv + bv -> Vt bf16}
//     + side-job {Wo transpose -> Wot global}
// 32x64 tile, grid (256,4) = 1024 blocks -> 4 blocks/CU
__global__ __launch_bounds__(256, 4) void prep_kernel(
    const float* __restrict__ value, const float* __restrict__ Wv,
    const float* __restrict__ bv, const float* __restrict__ Wo,
    unsigned short* __restrict__ Vt, unsigned short* __restrict__ Wot) {
    const int tid = threadIdx.x;
    const int wave = tid >> 6, lane = tid & 63;
    const int lm = lane & 15, q = lane >> 4;
    const int rh = wave >> 1;          // row half (16 rows each)
    const int nh = wave & 1;           // n half (32 cols each)
    const int m0 = blockIdx.x * 32;
    const int n0 = blockIdx.y * 64;

    __shared__ __align__(16) unsigned short Wlds[64][264];   // [n-local][k] bf16

    // side job: Wo transpose (64 elements per block, 1024 blocks cover 64K)
    {
        int bid = blockIdx.y * 256 + blockIdx.x;
        if (tid < 64) {
            int e = bid * 64 + tid;
            int k = e >> 8, n = e & 255;
            Wot[n * 256 + k] = f2bf(Wo[k * 256 + n]);
        }
    }

    // stage Wv[0:256][n0:n0+64] -> Wlds[n][k], coalesced f32 reads
    {
        int krow = tid >> 4;           // 0..15
        int nrel = (tid & 15) * 4;     // 0..60
#pragma unroll
        for (int p = 0; p < 16; p++) {
            int k = p * 16 + krow;
            f32x4 w = *reinterpret_cast<const f32x4*>(Wv + (size_t)k * 256 + n0 + nrel);
            Wlds[nrel + 0][k] = f2bf(w[0]);
            Wlds[nrel + 1][k] = f2bf(w[1]);
            Wlds[nrel + 2][k] = f2bf(w[2]);
            Wlds[nrel + 3][k] = f2bf(w[3]);
        }
    }
    __syncthreads();

    const int nl0 = nh * 32 + lm;          // local n, fragment 0
    const int nl1 = nh * 32 + 16 + lm;     // local n, fragment 1
    const int arow = m0 + rh * 16 + lm;

    f32x4 acc[2];
    acc[0] = (f32x4)(0.f); acc[1] = (f32x4)(0.f);

    const float* ap = value + (size_t)arow * 256;
    f32x4 pa0 = *reinterpret_cast<const f32x4*>(ap + q * 8);
    f32x4 pa1 = *reinterpret_cast<const f32x4*>(ap + q * 8 + 4);

    for (int k0 = 0; k0 < 256; k0 += 32) {
        f32x4 a0 = pa0, a1 = pa1;
        if (k0 < 224) {
            int kq = k0 + 32 + q * 8;
            pa0 = *reinterpret_cast<const f32x4*>(ap + kq);
            pa1 = *reinterpret_cast<const f32x4*>(ap + kq + 4);
        }
        bf16x8 b0 = *reinterpret_cast<const bf16x8*>(&Wlds[nl0][k0 + q * 8]);
        bf16x8 b1 = *reinterpret_cast<const bf16x8*>(&Wlds[nl1][k0 + q * 8]);
        bf16x8 afr;
#pragma unroll
        for (int e = 0; e < 4; e++) afr[e] = (short)f2bf(a0[e]);
#pragma unroll
        for (int e = 0; e < 4; e++) afr[4 + e] = (short)f2bf(a1[e]);
        acc[0] = __builtin_amdgcn_mfma_f32_16x16x32_bf16(afr, b0, acc[0], 0, 0, 0);
        acc[1] = __builtin_amdgcn_mfma_f32_16x16x32_bf16(afr, b1, acc[1], 0, 0, 0);
    }

    int mrow = m0 + rh * 16 + q * 4;       // rows mrow..mrow+3
    int b = mrow >> 11;
    int j = mrow & 2047;
#pragma unroll
    for (int nf = 0; nf < 2; nf++) {
        int n = n0 + nh * 32 + nf * 16 + lm;
        float bias_n = bv[n];
        const f32x4& a = acc[nf];
        unsigned short* dst = Vt + (size_t)b * (D * L) + (size_t)n * L + j;
        ushort4 pk;
        pk.x = f2bf(a[0] + bias_n);
        pk.y = f2bf(a[1] + bias_n);
        pk.z = f2bf(a[2] + bias_n);
        pk.w = f2bf(a[3] + bias_n);
        *reinterpret_cast<ushort4*>(dst) = pk;
    }
}

// --- fused mask + no-max softmax + P@V + /l + @Wo + bo -> out -----------
// r4 skeleton + (1) full double-buffering: next j-tile's Vt fragments AND
// logits issue BEFORE the barrier -> a whole iteration of latency hiding;
// (2) XCD-chunked block swizzle: blocks with the same batch land on the
// same XCD, so each XCD's 4MB L2 holds just 1MB of Vt (no thrash).
__global__ __launch_bounds__(256, 2) void attn_kernel(
    const float* __restrict__ atten, const float* __restrict__ mask,
    const int* __restrict__ pad, const unsigned short* __restrict__ Vt,
    const unsigned short* __restrict__ Wot, const float* __restrict__ bo,
    float* __restrict__ out) {
    const int bid = blockIdx.x;        // 0..511
    const int g = (bid & 7) * 64 + (bid >> 3);   // XCD-chunked: XCD pair -> one batch
    const int b = g >> 7;
    const int i0 = (g & 127) * 16;
    const int tid = threadIdx.x;
    const int wave = tid >> 6, lane = tid & 63;
    const int lm = lane & 15, q = lane >> 4;
    const int r = tid >> 4;            // softmax row 0..15
    const int c = (tid & 15) * 8;      // j offset within 128-tile

    __shared__ __align__(16) unsigned short Plds[2][16][136];
    __shared__ __align__(16) unsigned short A_lds[16][264];
    __shared__ float l_lds[16];

    f32x4 acc[4];
#pragma unroll
    for (int nf = 0; nf < 4; nf++) acc[nf] = (f32x4)(0.f);
    float lsum = 0.f;

    const size_t rowoff = ((size_t)(b * L + i0 + r)) * L + c;
    const float* at_p = atten + rowoff;
    const float* mk_p = mask + rowoff;
    const int*   pd_p = pad + rowoff;
    const unsigned short* vt_b = Vt + (size_t)b * (D * L) + q * 8;

    // double-buffered register state: tile logits + Vt fragments
    f32x4 laA0, laA1, lmA0, lmA1, laB0, laB1, lmB0, lmB1;
    i32x4 lpA0, lpA1, lpB0, lpB1;
    bf16x8 bfrA[4][4], bfrB[4][4];

    // prefetch tile 0 into A
    laA0 = *reinterpret_cast<const f32x4*>(at_p);
    laA1 = *reinterpret_cast<const f32x4*>(at_p + 4);
    lmA0 = *reinterpret_cast<const f32x4*>(mk_p);
    lmA1 = *reinterpret_cast<const f32x4*>(mk_p + 4);
    lpA0 = *reinterpret_cast<const i32x4*>(pd_p);
    lpA1 = *reinterpret_cast<const i32x4*>(pd_p + 4);
#pragma unroll
    for (int kk = 0; kk < 4; kk++)
#pragma unroll
        for (int nf = 0; nf < 4; nf++) {
            int n = wave * 64 + nf * 16 + lm;
            bfrA[kk][nf] = *reinterpret_cast<const bf16x8*>(
                vt_b + (size_t)n * L + kk * 32);
        }

    for (int jt = 0; jt < 16; jt += 2) {
        // ================= even tile: consume A, prefetch B ==============
        {
            const int j0 = jt * 128;
            bf16x8 pk;
#pragma unroll
            for (int e = 0; e < 4; e++) {
                float sv = (lmA0[e] < 0.5f) ? NEG_FLT_MAX : laA0[e];
                sv = (lpA0[e] == 0) ? -INFINITY : sv;
                float pv = __expf(sv);
                lsum += pv;
                pk[e] = (short)f2bf(pv);
                float sw = (lmA1[e] < 0.5f) ? NEG_FLT_MAX : laA1[e];
                sw = (lpA1[e] == 0) ? -INFINITY : sw;
                float pw = __expf(sw);
                lsum += pw;
                pk[4 + e] = (short)f2bf(pw);
            }
            *reinterpret_cast<bf16x8*>(&Plds[0][r][c]) = pk;
            // prefetch tile jt+1 into B (jt+1 <= 15 always)
            {
                const int jn = j0 + 128;
                laB0 = *reinterpret_cast<const f32x4*>(at_p + jn);
                laB1 = *reinterpret_cast<const f32x4*>(at_p + jn + 4);
                lmB0 = *reinterpret_cast<const f32x4*>(mk_p + jn);
                lmB1 = *reinterpret_cast<const f32x4*>(mk_p + jn + 4);
                lpB0 = *reinterpret_cast<const i32x4*>(pd_p + jn);
                lpB1 = *reinterpret_cast<const i32x4*>(pd_p + jn + 4);
#pragma unroll
                for (int kk = 0; kk < 4; kk++)
#pragma unroll
                    for (int nf = 0; nf < 4; nf++) {
                        int n = wave * 64 + nf * 16 + lm;
                        bfrB[kk][nf] = *reinterpret_cast<const bf16x8*>(
                            vt_b + (size_t)n * L + jn + kk * 32);
                    }
            }
            __syncthreads();
#pragma unroll
            for (int kk = 0; kk < 4; kk++) {
                bf16x8 afr = *reinterpret_cast<const bf16x8*>(
                    &Plds[0][lm][kk * 32 + q * 8]);
#pragma unroll
                for (int nf = 0; nf < 4; nf++)
                    acc[nf] = __builtin_amdgcn_mfma_f32_16x16x32_bf16(
                        afr, bfrA[kk][nf], acc[nf], 0, 0, 0);
            }
        }
        // ================= odd tile: consume B, prefetch A ===============
        {
            const int j0 = jt * 128 + 128;
            bf16x8 pk;
#pragma unroll
            for (int e = 0; e < 4; e++) {
                float sv = (lmB0[e] < 0.5f) ? NEG_FLT_MAX : laB0[e];
                sv = (lpB0[e] == 0) ? -INFINITY : sv;
                float pv = __expf(sv);
                lsum += pv;
                pk[e] = (short)f2bf(pv);
                float sw = (lmB1[e] < 0.5f) ? NEG_FLT_MAX : laB1[e];
                sw = (lpB1[e] == 0) ? -INFINITY : sw;
                float pw = __expf(sw);
                lsum += pw;
                pk[4 + e] = (short)f2bf(pw);
            }
            *reinterpret_cast<bf16x8*>(&Plds[1][r][c]) = pk;
            if (jt < 14) {             // prefetch tile jt+2 into A
                const int jn = j0 + 128;
                laA0 = *reinterpret_cast<const f32x4*>(at_p + jn);
                laA1 = *reinterpret_cast<const f32x4*>(at_p + jn + 4);
                lmA0 = *reinterpret_cast<const f32x4*>(mk_p + jn);
                lmA1 = *reinterpret_cast<const f32x4*>(mk_p + jn + 4);
                lpA0 = *reinterpret_cast<const i32x4*>(pd_p + jn);
                lpA1 = *reinterpret_cast<const i32x4*>(pd_p + jn + 4);
#pragma unroll
                for (int kk = 0; kk < 4; kk++)
#pragma unroll
                    for (int nf = 0; nf < 4; nf++) {
                        int n = wave * 64 + nf * 16 + lm;
                        bfrA[kk][nf] = *reinterpret_cast<const bf16x8*>(
                            vt_b + (size_t)n * L + jn + kk * 32);
                    }
            }
            __syncthreads();
#pragma unroll
            for (int kk = 0; kk < 4; kk++) {
                bf16x8 afr = *reinterpret_cast<const bf16x8*>(
                    &Plds[1][lm][kk * 32 + q * 8]);
#pragma unroll
                for (int nf = 0; nf < 4; nf++)
                    acc[nf] = __builtin_amdgcn_mfma_f32_16x16x32_bf16(
                        afr, bfrB[kk][nf], acc[nf], 0, 0, 0);
            }
        }
    }

    // deferred l-reduction: 16 threads (consecutive tids) share row r
    lsum += __shfl_xor(lsum, 1);
    lsum += __shfl_xor(lsum, 2);
    lsum += __shfl_xor(lsum, 4);
    lsum += __shfl_xor(lsum, 8);
    if ((tid & 15) == 0) l_lds[r] = lsum;
    __syncthreads();

    // normalize, pack bf16 A for the out-projection
    float linv[4];
#pragma unroll
    for (int rg = 0; rg < 4; rg++) linv[rg] = 1.f / l_lds[q * 4 + rg];
#pragma unroll
    for (int nf = 0; nf < 4; nf++) {
        int n = wave * 64 + nf * 16 + lm;
#pragma unroll
        for (int rg = 0; rg < 4; rg++)
            A_lds[q * 4 + rg][n] = f2bf(acc[nf][rg] * linv[rg]);
    }
    __syncthreads();

    // out-projection: [16][256] @ Wo + bo, each wave 64 n
    f32x4 oacc[4];
#pragma unroll
    for (int nf = 0; nf < 4; nf++) oacc[nf] = (f32x4)(0.f);
    for (int k0 = 0; k0 < 256; k0 += 32) {
        bf16x8 afr = *reinterpret_cast<const bf16x8*>(&A_lds[lm][k0 + q * 8]);
#pragma unroll
        for (int nf = 0; nf < 4; nf++) {
            int n = wave * 64 + nf * 16 + lm;
            bf16x8 bfrW = *reinterpret_cast<const bf16x8*>(
                Wot + (size_t)n * 256 + k0 + q * 8);
            oacc[nf] = __builtin_amdgcn_mfma_f32_16x16x32_bf16(
                afr, bfrW, oacc[nf], 0, 0, 0);
        }
    }
#pragma unroll
    for (int nf = 0; nf < 4; nf++) {
        int n = wave * 64 + nf * 16 + lm;
        float bias_n = bo[n];
#pragma unroll
        for (int rg = 0; rg < 4; rg++)
            out[((size_t)(b * L + i0 + q * 4 + rg)) * 256 + n] = oacc[nf][rg] + bias_n;
    }
}

extern "C" void kernel_launch(void* const* d_in, const int* in_sizes, int n_in,
                              void* d_out, int out_size, void* d_ws, size_t ws_size,
                              hipStream_t stream) {
    (void)in_sizes; (void)n_in; (void)out_size; (void)ws_size;
    const float* atten = (const float*)d_in[0];
    const float* value = (const float*)d_in[1];
    const float* mask  = (const float*)d_in[2];
    const int*   pad   = (const int*)d_in[3];
    const float* Wv    = (const float*)d_in[4];
    const float* bv    = (const float*)d_in[5];
    const float* Wo    = (const float*)d_in[6];
    const float* bo    = (const float*)d_in[7];
    float* out = (float*)d_out;

    char* ws = (char*)d_ws;
    unsigned short* Vt  = (unsigned short*)(ws);              // 4 MB  bf16 [B][D][L]
    unsigned short* Wot = (unsigned short*)(ws + 4194304);    // 128 KB

    prep_kernel<<<dim3(256, 4), 256, 0, stream>>>(value, Wv, bv, Wo, Vt, Wot);
    attn_kernel<<<512, 256, 0, stream>>>(atten, mask, pad, Vt, Wot, bo, out);
}